// Round 9
// baseline (266.404 us; speedup 1.0000x reference)
//
#include <hip/hip_runtime.h>
#include <math.h>

#define H 128
typedef unsigned int u32;
typedef unsigned long long u64;
typedef __attribute__((ext_vector_type(8))) short short8;
typedef __attribute__((ext_vector_type(4))) float floatx4;

#define XS_STRIDE 136   // bf16 elems per padded row (128 + 8) -> 272B
#define CS_STRIDE 40    // counts row stride (80B) -> conflict-free b128 reads
#define SBCAP 640       // records per sub-tail (mean 383, 13 sigma margin)
#define NSUB 8          // sub-tails per bucket
#define BUCKCAP (SBCAP * NSUB)   // 5120 CSR slots per bucket region

__device__ __forceinline__ float sigmoid_f(float x) {
    return 1.0f / (1.0f + __expf(-x));
}
__device__ __forceinline__ float tanh_f(float x) {
    float t = __expf(-2.0f * fabsf(x));
    float r = (1.0f - t) / (1.0f + t);
    return copysignf(r, x);
}
// f32 -> bf16 bits, round-to-nearest-even (finite inputs)
__device__ __forceinline__ unsigned short f2bf(float x) {
    u32 u = __float_as_uint(x);
    return (unsigned short)((u + 0x7fffu + ((u >> 16) & 1u)) >> 16);
}
__device__ __forceinline__ float bf2f(unsigned short s) {
    return __uint_as_float(((u32)s) << 16);
}
__device__ __forceinline__ float bf_lo32(u32 u) { return __uint_as_float(u << 16); }
__device__ __forceinline__ float bf_hi32(u32 u) { return __uint_as_float(u & 0xffff0000u); }

// ---------------------------------------------------------------------------
// Fused pre-pass: [blocks 0..HB)   h (f32) -> h_b (bf16)
//                 [HB..HB+DB)      ohead[]=-1, bcnt[]=0
//                 [HB+DB..)        weight prep (W_c fold, embW', Whh swizzle)
// Swizzle (B-frag, 16x16x32): frag[((gtile*4+kc)*64 + l)*8 + i] =
//   W[(gtile*16 + (l&15))][kc*32 + (l>>4)*8 + i]
// ---------------------------------------------------------------------------
__global__ __launch_bounds__(256) void fused_pre_kernel(
    const float* __restrict__ h, unsigned short* __restrict__ h_b, int total8,
    int* __restrict__ ohead, int* __restrict__ bcnt, int N, int NS,
    const float* __restrict__ Wih, const float* __restrict__ Whh,
    const float* __restrict__ Wm,  const float* __restrict__ emb,
    const float* __restrict__ bm,
    unsigned short* __restrict__ Wcs, unsigned short* __restrict__ Whhs,
    unsigned short* __restrict__ embWs, int HB, int DB)
{
    int b = blockIdx.x;
    if (b < HB) {
        int idx = b * 256 + threadIdx.x;
        if (idx >= total8) return;
        const float4* p = (const float4*)(h + (size_t)idx * 8);
        float4 a = p[0], bb = p[1];
        short8 v;
        v[0] = (short)f2bf(a.x);  v[1] = (short)f2bf(a.y);
        v[2] = (short)f2bf(a.z);  v[3] = (short)f2bf(a.w);
        v[4] = (short)f2bf(bb.x); v[5] = (short)f2bf(bb.y);
        v[6] = (short)f2bf(bb.z); v[7] = (short)f2bf(bb.w);
        *(short8*)(h_b + (size_t)idx * 8) = v;
        return;
    }
    if (b < HB + DB) {
        int idx = (b - HB) * 256 + threadIdx.x;
        if (idx < N) ohead[idx] = -1;
        else if (idx < N + NS) bcnt[idx - N] = 0;
        return;
    }
    int idx = (b - HB - DB) * 256 + threadIdx.x;
    if (idx < 49152) {
        // ---- W_c[g][k] = sum_c Wih[g][c] * Wm[c][k], f32 acc -> bf16 swizzled
        int g = idx >> 7;          // 0..383
        int k = idx & 127;
        float acc = 0.f;
#pragma unroll 4
        for (int c = 0; c < H; ++c)
            acc += Wih[(size_t)g * H + c] * Wm[(size_t)c * H + k];
        int gate = g >> 7;
        int wi = g & 127;
        int j = wi >> 4, m = wi & 15;
        int kc = k >> 5, q = (k >> 3) & 3, i = k & 7;
        int l = q * 16 + m;
        Wcs[(size_t)(((gate * 8 + j) * 4 + kc) * 64 + l) * 8 + i] = f2bf(acc);
    } else if (idx < 61440) {
        // ---- embW'[t][g] = sum_j (emb[t][j]+bm[j])*Wih[g][j], K=32 frag
        int s = idx - 49152;       // 0..12287
        int i = s & 7;
        int l = (s >> 3) & 63;
        int jb = s >> 9;           // gate*8 + j
        int gate = jb >> 3, jj = jb & 7;
        int q = l >> 4, m = l & 15;
        int t = q * 8 + i;         // edge type (K index)
        unsigned short v = 0;
        if (t < 9) {
            int g = gate * 128 + jj * 16 + m;
            float acc = 0.f;
#pragma unroll 4
            for (int jx = 0; jx < H; ++jx)
                acc += (emb[(size_t)t * H + jx] + bm[jx]) * Wih[(size_t)g * H + jx];
            v = f2bf(acc);
        }
        embWs[s] = v;
    } else if (idx < 67584) {
        // ---- Whh convert + swizzle
        int t2 = idx - 61440;      // 0..6143
        int l  = t2 & 63;
        int kc = (t2 >> 6) & 3;
        int jr = t2 >> 8;
        int m = l & 15, q = l >> 4;
        size_t srco = (size_t)(jr * 16 + m) * H + kc * 32 + q * 8;
        const float4* s0 = (const float4*)(Whh + srco);
        float4 a = s0[0], bb = s0[1];
        short8 v;
        v[0] = (short)f2bf(a.x);  v[1] = (short)f2bf(a.y);
        v[2] = (short)f2bf(a.z);  v[3] = (short)f2bf(a.w);
        v[4] = (short)f2bf(bb.x); v[5] = (short)f2bf(bb.y);
        v[6] = (short)f2bf(bb.z); v[7] = (short)f2bf(bb.w);
        *(short8*)(Whhs + (size_t)t2 * 8) = v;
    }
}

// ---------------------------------------------------------------------------
// Pass 1: bin edges into NB buckets x 8 sub-tails (bucket = dst>>8).
// Only ~1568 hot tail lines -> writes combine in L2 (8 x 8B records/line),
// ~1x write amplification vs 16x for per-node scatter. Record:
// [src:48][type:8][dst&255:8]. Overflow (13-sigma) -> per-node linked list.
// ---------------------------------------------------------------------------
__global__ __launch_bounds__(256) void fill_bin_kernel(
    const int* __restrict__ eidx, const int* __restrict__ etype,
    int* __restrict__ bcnt, u64* __restrict__ brec,
    int* __restrict__ ohead, int* __restrict__ onext, int* __restrict__ opk,
    int E)
{
    int e = blockIdx.x * 256 + threadIdx.x;
    if (e >= E) return;
    int src = eidx[e];
    int dst = eidx[E + e];
    int t = etype[e];
    t = t < 0 ? 0 : (t > 8 ? 8 : t);
    int ctr = (dst >> 8) * NSUB + (e & (NSUB - 1));
    int p = atomicAdd(&bcnt[ctr], 1);
    if (p < SBCAP) {
        brec[(size_t)ctr * SBCAP + p] =
            ((u64)(u32)src << 16) | ((u64)t << 8) | (u64)(dst & 255);
    } else {
        opk[e] = src | (t << 24);
        int old = atomicExch(&ohead[dst], e);
        onext[e] = old;
    }
}

// ---------------------------------------------------------------------------
// Pass 2: one block per bucket (256 nodes). Stage records in LDS, histogram
// + scan -> per-node deg/start, scatter dense CSR rows into the bucket's
// contiguous region (L2-hot). All global I/O coalesced.
// ---------------------------------------------------------------------------
__global__ __launch_bounds__(256) void csr_kernel(
    const u64* __restrict__ brec, const int* __restrict__ bcnt,
    int* __restrict__ deg, int* __restrict__ start,
    int* __restrict__ packed, int N)
{
    __shared__ u64 recs[BUCKCAP];     // 40960 B
    __shared__ int ldeg[256];
    __shared__ int lscan[256];
    __shared__ int lpos[256];

    int b = blockIdx.x;
    int tid = threadIdx.x;
    int n0 = b << 8;

    int c[NSUB], base[NSUB];
    int tot = 0;
#pragma unroll
    for (int s = 0; s < NSUB; ++s) {
        int cc = bcnt[b * NSUB + s];
        cc = cc < SBCAP ? cc : SBCAP;
        c[s] = cc;
        base[s] = tot;
        tot += cc;
    }
#pragma unroll
    for (int s = 0; s < NSUB; ++s) {
        const u64* srcp = brec + (size_t)(b * NSUB + s) * SBCAP;
        for (int i = tid; i < c[s]; i += 256) recs[base[s] + i] = srcp[i];
    }
    ldeg[tid] = 0;
    __syncthreads();

    for (int i = tid; i < tot; i += 256)
        atomicAdd(&ldeg[(u32)recs[i] & 255u], 1);
    __syncthreads();

    lscan[tid] = ldeg[tid];
    __syncthreads();
    for (int d = 1; d < 256; d <<= 1) {
        int v = (tid >= d) ? lscan[tid - d] : 0;
        __syncthreads();
        lscan[tid] += v;
        __syncthreads();
    }
    int st = lscan[tid] - ldeg[tid];     // exclusive prefix
    lpos[tid] = st;
    int n = n0 + tid;
    int gbase = b * BUCKCAP;
    if (n < N) {
        deg[n] = ldeg[tid];
        start[n] = gbase + st;
    }
    __syncthreads();

    for (int i = tid; i < tot; i += 256) {
        u64 r = recs[i];
        int d = (u32)r & 255u;
        int t = ((u32)r >> 8) & 255u;
        int src = (int)(r >> 16);
        int p = atomicAdd(&lpos[d], 1);
        packed[gbase + p] = src | (t << 24);
    }
}

// ---------------------------------------------------------------------------
// Gather over dense CSR rows: S[n] = sum h_b[src], cnt[n] packed type counts.
// One wave per node; row reads contiguous + independent, 8-wide unrolled.
// Overflow chain (never taken in practice) guarantees correctness.
// ---------------------------------------------------------------------------
__global__ __launch_bounds__(256) void gather_csr_kernel(
    const unsigned short* __restrict__ h_b,
    const int* __restrict__ deg, const int* __restrict__ start,
    const int* __restrict__ packed,
    const int* __restrict__ ohead, const int* __restrict__ onext,
    const int* __restrict__ opk,
    unsigned short* __restrict__ S_b, u64* __restrict__ cnt, int N)
{
    int n = blockIdx.x * 4 + (threadIdx.x >> 6);
    if (n >= N) return;
    int lane = threadIdx.x & 63;
    int m = deg[n];
    const int* row = packed + start[n];

    float ax = 0.f, ay = 0.f;
    u64 c = 0;
    int i = 0;
    for (; i + 8 <= m; i += 8) {
        int u0 = row[i + 0];
        int u1 = row[i + 1];
        int u2 = row[i + 2];
        int u3 = row[i + 3];
        int u4 = row[i + 4];
        int u5 = row[i + 5];
        int u6 = row[i + 6];
        int u7 = row[i + 7];
        u32 x0 = *((const u32*)(h_b + (size_t)(u0 & 0xffffff) * H) + lane);
        u32 x1 = *((const u32*)(h_b + (size_t)(u1 & 0xffffff) * H) + lane);
        u32 x2 = *((const u32*)(h_b + (size_t)(u2 & 0xffffff) * H) + lane);
        u32 x3 = *((const u32*)(h_b + (size_t)(u3 & 0xffffff) * H) + lane);
        u32 x4 = *((const u32*)(h_b + (size_t)(u4 & 0xffffff) * H) + lane);
        u32 x5 = *((const u32*)(h_b + (size_t)(u5 & 0xffffff) * H) + lane);
        u32 x6 = *((const u32*)(h_b + (size_t)(u6 & 0xffffff) * H) + lane);
        u32 x7 = *((const u32*)(h_b + (size_t)(u7 & 0xffffff) * H) + lane);
        c += (1ull << (7 * (u0 >> 24))) + (1ull << (7 * (u1 >> 24)))
           + (1ull << (7 * (u2 >> 24))) + (1ull << (7 * (u3 >> 24)))
           + (1ull << (7 * (u4 >> 24))) + (1ull << (7 * (u5 >> 24)))
           + (1ull << (7 * (u6 >> 24))) + (1ull << (7 * (u7 >> 24)));
        ax += bf_lo32(x0) + bf_lo32(x1) + bf_lo32(x2) + bf_lo32(x3)
            + bf_lo32(x4) + bf_lo32(x5) + bf_lo32(x6) + bf_lo32(x7);
        ay += bf_hi32(x0) + bf_hi32(x1) + bf_hi32(x2) + bf_hi32(x3)
            + bf_hi32(x4) + bf_hi32(x5) + bf_hi32(x6) + bf_hi32(x7);
    }
    for (; i + 4 <= m; i += 4) {
        int u0 = row[i + 0];
        int u1 = row[i + 1];
        int u2 = row[i + 2];
        int u3 = row[i + 3];
        u32 x0 = *((const u32*)(h_b + (size_t)(u0 & 0xffffff) * H) + lane);
        u32 x1 = *((const u32*)(h_b + (size_t)(u1 & 0xffffff) * H) + lane);
        u32 x2 = *((const u32*)(h_b + (size_t)(u2 & 0xffffff) * H) + lane);
        u32 x3 = *((const u32*)(h_b + (size_t)(u3 & 0xffffff) * H) + lane);
        c += (1ull << (7 * (u0 >> 24))) + (1ull << (7 * (u1 >> 24)))
           + (1ull << (7 * (u2 >> 24))) + (1ull << (7 * (u3 >> 24)));
        ax += bf_lo32(x0) + bf_lo32(x1) + bf_lo32(x2) + bf_lo32(x3);
        ay += bf_hi32(x0) + bf_hi32(x1) + bf_hi32(x2) + bf_hi32(x3);
    }
    for (; i < m; ++i) {
        int u = row[i];
        u32 x = *((const u32*)(h_b + (size_t)(u & 0xffffff) * H) + lane);
        c += 1ull << (7 * (u >> 24));
        ax += bf_lo32(x);
        ay += bf_hi32(x);
    }
    int oh = ohead[n];
    if (oh >= 0) {
        // overflow chain (essentially never taken; wave-uniform branch)
        int ecur = oh;
        while (ecur >= 0) {
            int u = opk[ecur];
            u32 x = *((const u32*)(h_b + (size_t)(u & 0xffffff) * H) + lane);
            c += 1ull << (7 * (u >> 24));
            ax += bf_lo32(x);
            ay += bf_hi32(x);
            ecur = onext[ecur];
        }
    }
    u32 o = (u32)f2bf(ax) | ((u32)f2bf(ay) << 16);
    *((u32*)(S_b + (size_t)n * H) + lane) = o;
    if (lane == 0) cnt[n] = c;
}

// ---------------------------------------------------------------------------
// Fused GRU (MFMA). Block = (64-node tile) x (jhalf of 4 j-tiles); 4 waves,
// each wave owns ONE j-tile and loops 4 row-tiles (accs register-resident,
// weights loaded once per kc). Grid = 2x node-tiles (~1564 blocks) for
// latency hiding; LDS 39.9KB -> 4 resident blocks/CU. (r4-proven structure.)
//   aR = counts@embW_r + S@Wc_r^T + h@Whh_r^T    (gate-shared accumulators)
//   aZ = counts@embW_z + S@Wc_z^T + h@Whh_z^T
//   aIn = counts@embW_n + S@Wc_n^T ; aHn = h@Whh_n^T
// ---------------------------------------------------------------------------
__global__ __launch_bounds__(256, 4) void gru_mfma_kernel(
    const unsigned short* __restrict__ S_b, const unsigned short* __restrict__ h_b,
    const unsigned short* __restrict__ Wcs, const unsigned short* __restrict__ Whhs,
    const unsigned short* __restrict__ embWs,
    const float* __restrict__ bih, const float* __restrict__ bhh,
    const u64* __restrict__ cnt,
    const int* __restrict__ numn, float* __restrict__ out, int N)
{
    __shared__ unsigned short xs[64 * XS_STRIDE];    // 17408 B
    __shared__ unsigned short hsb[64 * XS_STRIDE];   // 17408 B
    __shared__ unsigned short cs[64 * CS_STRIDE];    //  5120 B

    int tid = threadIdx.x;
    int bx = blockIdx.x;
    int node0 = (bx >> 1) * 64;
    int jhalf = bx & 1;

    int lane = tid & 63;
    int wv = tid >> 6;
    int j = jhalf * 4 + wv;      // this wave's j-tile (0..7)

    // prefetch emb fragments (independent of staging; completes under barrier)
    short8 er = *(const short8*)(embWs + (size_t)((0 * 8 + j) * 64 + lane) * 8);
    short8 ez = *(const short8*)(embWs + (size_t)((1 * 8 + j) * 64 + lane) * 8);
    short8 en = *(const short8*)(embWs + (size_t)((2 * 8 + j) * 64 + lane) * 8);

    for (int c = tid; c < 1024; c += 256) {
        int r = c >> 4;
        int k8 = (c & 15) << 3;
        int n = node0 + r;
        int nc = n < N ? n : N - 1;
        *(short8*)(&xs[r * XS_STRIDE + k8]) =
            *(const short8*)(S_b + (size_t)nc * H + k8);
        *(short8*)(&hsb[r * XS_STRIDE + k8]) =
            *(const short8*)(h_b + (size_t)nc * H + k8);
    }
    {
        // counts tile: row r, type-group tg covers t = tg*8 .. tg*8+7 (t<9 live)
        int r = tid >> 2, tg = tid & 3;
        int n = node0 + r;
        u64 cv = cnt[n < N ? n : N - 1];
        short8 v = {0, 0, 0, 0, 0, 0, 0, 0};
        if (tg == 0) {
#pragma unroll
            for (int i = 0; i < 8; ++i)
                v[i] = (short)f2bf((float)((u32)(cv >> (7 * i)) & 127u));
        } else if (tg == 1) {
            v[0] = (short)f2bf((float)((u32)(cv >> 56) & 127u));
        }
        *(short8*)(&cs[r * CS_STRIDE + tg * 8]) = v;
    }
    __syncthreads();

    int am = lane & 15;
    int aq = lane >> 4;

    int num_nodes = numn[0];
    floatx4 zero = {0.f, 0.f, 0.f, 0.f};

    floatx4 aR[4], aZ[4], aIn[4], aHn[4];
#pragma unroll
    for (int rt = 0; rt < 4; ++rt) {
        short8 acn = *(const short8*)(&cs[(rt * 16 + am) * CS_STRIDE + aq * 8]);
        aR[rt]  = __builtin_amdgcn_mfma_f32_16x16x32_bf16(acn, er, zero, 0, 0, 0);
        aZ[rt]  = __builtin_amdgcn_mfma_f32_16x16x32_bf16(acn, ez, zero, 0, 0, 0);
        aIn[rt] = __builtin_amdgcn_mfma_f32_16x16x32_bf16(acn, en, zero, 0, 0, 0);
        aHn[rt] = zero;
    }
#pragma unroll
    for (int kc = 0; kc < 4; ++kc) {
        size_t c_r = (size_t)(((0 * 8 + j) * 4 + kc) * 64 + lane) * 8;
        size_t c_z = (size_t)(((1 * 8 + j) * 4 + kc) * 64 + lane) * 8;
        size_t c_n = (size_t)(((2 * 8 + j) * 4 + kc) * 64 + lane) * 8;
        short8 bir = *(const short8*)(Wcs + c_r);
        short8 bhr = *(const short8*)(Whhs + c_r);
        short8 biz = *(const short8*)(Wcs + c_z);
        short8 bhz = *(const short8*)(Whhs + c_z);
        short8 bin = *(const short8*)(Wcs + c_n);
        short8 bhn = *(const short8*)(Whhs + c_n);
#pragma unroll
        for (int rt = 0; rt < 4; ++rt) {
            int arow = rt * 16 + am;
            short8 axv = *(const short8*)(&xs[arow * XS_STRIDE + kc * 32 + aq * 8]);
            short8 ahv = *(const short8*)(&hsb[arow * XS_STRIDE + kc * 32 + aq * 8]);
            aR[rt]  = __builtin_amdgcn_mfma_f32_16x16x32_bf16(axv, bir, aR[rt], 0, 0, 0);
            aR[rt]  = __builtin_amdgcn_mfma_f32_16x16x32_bf16(ahv, bhr, aR[rt], 0, 0, 0);
            aZ[rt]  = __builtin_amdgcn_mfma_f32_16x16x32_bf16(axv, biz, aZ[rt], 0, 0, 0);
            aZ[rt]  = __builtin_amdgcn_mfma_f32_16x16x32_bf16(ahv, bhz, aZ[rt], 0, 0, 0);
            aIn[rt] = __builtin_amdgcn_mfma_f32_16x16x32_bf16(axv, bin, aIn[rt], 0, 0, 0);
            aHn[rt] = __builtin_amdgcn_mfma_f32_16x16x32_bf16(ahv, bhn, aHn[rt], 0, 0, 0);
        }
    }
    int c = j * 16 + am;
    float b_r = bih[c]       + bhh[c];
    float b_z = bih[128 + c] + bhh[128 + c];
    float b_in = bih[256 + c], b_hn = bhh[256 + c];
#pragma unroll
    for (int rt = 0; rt < 4; ++rt) {
#pragma unroll
        for (int q = 0; q < 4; ++q) {
            int m = rt * 16 + aq * 4 + q;
            int node = node0 + m;
            if (node < N) {
                float r  = sigmoid_f(aR[rt][q] + b_r);
                float z  = sigmoid_f(aZ[rt][q] + b_z);
                float nv = tanh_f((aIn[rt][q] + b_in) + r * (aHn[rt][q] + b_hn));
                float hv = bf2f(hsb[m * XS_STRIDE + c]);
                float o  = (1.0f - z) * nv + z * hv;
                out[(size_t)node * H + c] = (node < num_nodes) ? o : 0.0f;
            }
        }
    }
}

extern "C" void kernel_launch(void* const* d_in, const int* in_sizes, int n_in,
                              void* d_out, int out_size, void* d_ws, size_t ws_size,
                              hipStream_t stream) {
    const float* h    = (const float*)d_in[0];
    const int*  eidx  = (const int*)d_in[1];
    const int*  etype = (const int*)d_in[2];
    const int*  numn  = (const int*)d_in[3];
    const float* Wm   = (const float*)d_in[4];
    const float* bm   = (const float*)d_in[5];
    const float* emb  = (const float*)d_in[6];
    const float* Wih  = (const float*)d_in[7];
    const float* Whh  = (const float*)d_in[8];
    const float* bih  = (const float*)d_in[9];
    const float* bhh  = (const float*)d_in[10];

    int N = in_sizes[0] / H;
    int E = in_sizes[2];
    int NB = (N + 255) >> 8;        // buckets (256 nodes each)
    int NS = NB * NSUB;             // sub-tail counters

    // ws layout:
    unsigned short* S_b   = (unsigned short*)d_ws;               // N*H bf16
    unsigned short* h_b   = S_b + (size_t)N * H;                 // N*H bf16
    unsigned short* Wcs   = h_b + (size_t)N * H;                 // 3*H*H (swizzled)
    unsigned short* Whhs  = Wcs + 3 * H * H;                     // 3*H*H (swizzled)
    unsigned short* embWs = Whhs + 3 * H * H;                    // 12288
    u64* cnt    = (u64*)(embWs + 12288);                         // N (8B-aligned)
    int* deg    = (int*)(cnt + N);                               // N
    int* start  = deg + N;                                       // N
    int* ohead  = start + N;                                     // N
    int* bcnt   = ohead + N;                                     // NS
    u64* brec   = (u64*)(bcnt + ((NS + 1) & ~1));                // NS*SBCAP (8B-al)
    int* packed = (int*)(brec + (size_t)NS * SBCAP);             // NB*BUCKCAP
    int* onext  = packed + (size_t)NB * BUCKCAP;                 // E
    int* opk    = onext + E;                                     // E

    int total8 = N * H / 8;
    int HB = (total8 + 255) / 256;
    int DB = (N + NS + 255) / 256;
    int PB = 264;
    fused_pre_kernel<<<HB + DB + PB, 256, 0, stream>>>(
        h, h_b, total8, ohead, bcnt, N, NS, Wih, Whh, Wm, emb, bm,
        Wcs, Whhs, embWs, HB, DB);

    fill_bin_kernel<<<(E + 255) / 256, 256, 0, stream>>>(
        eidx, etype, bcnt, brec, ohead, onext, opk, E);

    csr_kernel<<<NB, 256, 0, stream>>>(brec, bcnt, deg, start, packed, N);

    gather_csr_kernel<<<(N + 3) / 4, 256, 0, stream>>>(
        h_b, deg, start, packed, ohead, onext, opk, S_b, cnt, N);

    int nblk = ((N + 63) / 64) * 2;
    gru_mfma_kernel<<<nblk, 256, 0, stream>>>(S_b, h_b, Wcs, Whhs, embWs,
                                              bih, bhh, cnt, numn, (float*)d_out, N);
}

// Round 10
// 206.305 us; speedup vs baseline: 1.2913x; 1.2913x over previous
//
#include <hip/hip_runtime.h>
#include <math.h>

#define H 128
typedef unsigned int u32;
typedef unsigned long long u64;
typedef __attribute__((ext_vector_type(8))) short short8;
typedef __attribute__((ext_vector_type(4))) float floatx4;

#define XS_STRIDE 136   // bf16 elems per padded row (128 + 8) -> 272B
#define CS_STRIDE 40    // counts row stride (80B) -> conflict-free b128 reads
#define ROWCAP 128      // dense CSR row capacity per node (4 chains x 32)

__device__ __forceinline__ float sigmoid_f(float x) {
    return 1.0f / (1.0f + __expf(-x));
}
__device__ __forceinline__ float tanh_f(float x) {
    float t = __expf(-2.0f * fabsf(x));
    float r = (1.0f - t) / (1.0f + t);
    return copysignf(r, x);
}
// f32 -> bf16 bits, round-to-nearest-even (finite inputs)
__device__ __forceinline__ unsigned short f2bf(float x) {
    u32 u = __float_as_uint(x);
    return (unsigned short)((u + 0x7fffu + ((u >> 16) & 1u)) >> 16);
}
__device__ __forceinline__ float bf2f(unsigned short s) {
    return __uint_as_float(((u32)s) << 16);
}
__device__ __forceinline__ float bf_lo32(u32 u) { return __uint_as_float(u << 16); }
__device__ __forceinline__ float bf_hi32(u32 u) { return __uint_as_float(u & 0xffff0000u); }

// ---------------------------------------------------------------------------
// Fused pre-pass: [blocks 0..HB)   h (f32) -> h_b (bf16)
//                 [HB..HB+DB)      head4[]=-1 (4N), ohead[]=-1 (N)
//                 [HB+DB..)        weight prep (W_c fold, embW', Whh swizzle)
// Swizzle (B-frag, 16x16x32): frag[((gtile*4+kc)*64 + l)*8 + i] =
//   W[(gtile*16 + (l&15))][kc*32 + (l>>4)*8 + i]
// ---------------------------------------------------------------------------
__global__ __launch_bounds__(256) void fused_pre_kernel(
    const float* __restrict__ h, unsigned short* __restrict__ h_b, int total8,
    int* __restrict__ head4, int* __restrict__ ohead, int N,
    const float* __restrict__ Wih, const float* __restrict__ Whh,
    const float* __restrict__ Wm,  const float* __restrict__ emb,
    const float* __restrict__ bm,
    unsigned short* __restrict__ Wcs, unsigned short* __restrict__ Whhs,
    unsigned short* __restrict__ embWs, int HB, int DB)
{
    int b = blockIdx.x;
    if (b < HB) {
        int idx = b * 256 + threadIdx.x;
        if (idx >= total8) return;
        const float4* p = (const float4*)(h + (size_t)idx * 8);
        float4 a = p[0], bb = p[1];
        short8 v;
        v[0] = (short)f2bf(a.x);  v[1] = (short)f2bf(a.y);
        v[2] = (short)f2bf(a.z);  v[3] = (short)f2bf(a.w);
        v[4] = (short)f2bf(bb.x); v[5] = (short)f2bf(bb.y);
        v[6] = (short)f2bf(bb.z); v[7] = (short)f2bf(bb.w);
        *(short8*)(h_b + (size_t)idx * 8) = v;
        return;
    }
    if (b < HB + DB) {
        int idx = (b - HB) * 256 + threadIdx.x;
        if (idx < 4 * N) head4[idx] = -1;
        else if (idx < 5 * N) ohead[idx - 4 * N] = -1;
        return;
    }
    int idx = (b - HB - DB) * 256 + threadIdx.x;
    if (idx < 49152) {
        // ---- W_c[g][k] = sum_c Wih[g][c] * Wm[c][k], f32 acc -> bf16 swizzled
        int g = idx >> 7;          // 0..383
        int k = idx & 127;
        float acc = 0.f;
#pragma unroll 4
        for (int c = 0; c < H; ++c)
            acc += Wih[(size_t)g * H + c] * Wm[(size_t)c * H + k];
        int gate = g >> 7;
        int wi = g & 127;
        int j = wi >> 4, m = wi & 15;
        int kc = k >> 5, q = (k >> 3) & 3, i = k & 7;
        int l = q * 16 + m;
        Wcs[(size_t)(((gate * 8 + j) * 4 + kc) * 64 + l) * 8 + i] = f2bf(acc);
    } else if (idx < 61440) {
        // ---- embW'[t][g] = sum_j (emb[t][j]+bm[j])*Wih[g][j], K=32 frag
        int s = idx - 49152;       // 0..12287
        int i = s & 7;
        int l = (s >> 3) & 63;
        int jb = s >> 9;           // gate*8 + j
        int gate = jb >> 3, jj = jb & 7;
        int q = l >> 4, m = l & 15;
        int t = q * 8 + i;         // edge type (K index)
        unsigned short v = 0;
        if (t < 9) {
            int g = gate * 128 + jj * 16 + m;
            float acc = 0.f;
#pragma unroll 4
            for (int jx = 0; jx < H; ++jx)
                acc += (emb[(size_t)t * H + jx] + bm[jx]) * Wih[(size_t)g * H + jx];
            v = f2bf(acc);
        }
        embWs[s] = v;
    } else if (idx < 67584) {
        // ---- Whh convert + swizzle
        int t2 = idx - 61440;      // 0..6143
        int l  = t2 & 63;
        int kc = (t2 >> 6) & 3;
        int jr = t2 >> 8;
        int m = l & 15, q = l >> 4;
        size_t srco = (size_t)(jr * 16 + m) * H + kc * 32 + q * 8;
        const float4* s0 = (const float4*)(Whh + srco);
        float4 a = s0[0], bb = s0[1];
        short8 v;
        v[0] = (short)f2bf(a.x);  v[1] = (short)f2bf(a.y);
        v[2] = (short)f2bf(a.z);  v[3] = (short)f2bf(a.w);
        v[4] = (short)f2bf(bb.x); v[5] = (short)f2bf(bb.y);
        v[6] = (short)f2bf(bb.z); v[7] = (short)f2bf(bb.w);
        *(short8*)(Whhs + (size_t)t2 * 8) = v;
    }
}

// ---------------------------------------------------------------------------
// Linked-list build (all writes coalesced by e; only a 4B L2-resident
// atomicExch is random -- proven cheap in r6/r7):
//   packed[e] = src | type<<24 ; nexte[e] = atomicExch(&head4[dst*4+(e&3)], e)
// ---------------------------------------------------------------------------
__global__ __launch_bounds__(256) void fill_ll_kernel(
    const int* __restrict__ eidx, const int* __restrict__ etype,
    int* __restrict__ head4, int* __restrict__ nexte,
    int* __restrict__ packed, int E)
{
    int e = blockIdx.x * 256 + threadIdx.x;
    if (e >= E) return;
    int src = eidx[e];
    int dst = eidx[E + e];
    int t = etype[e];
    t = t < 0 ? 0 : (t > 8 ? 8 : t);
    packed[e] = src | (t << 24);
    int old = atomicExch(&head4[(size_t)dst * 4 + (e & 3)], e);
    nexte[e] = old;
}

// ---------------------------------------------------------------------------
// LL -> dense CSR rows. PER-LANE chain chase: 64 independent chains per wave
// (16 nodes x 4 chains), records buffered in LDS (stride 33 -> bank-conflict
// free), then compact row written to slots[n*128..] by ONE lane group on ONE
// CU (no cross-XCD line ping-pong; ~3MB total writes vs 35MB scatter).
// Sub-chain overflow (>32, ~1e-23/chain) re-linked into ohead for gather.
// ---------------------------------------------------------------------------
__global__ __launch_bounds__(256) void ll2csr_kernel(
    const int* __restrict__ head4, int* __restrict__ nexte,
    const int* __restrict__ packed,
    int* __restrict__ slots, int* __restrict__ deg,
    int* __restrict__ ohead, int N)
{
    __shared__ int lbuf[256 * 33];    // 33792 B, per-thread 32-record area

    int tid = threadIdx.x;
    int lane = tid & 63;
    int wv = tid >> 6;
    int n = (blockIdx.x * 4 + wv) * 16 + (lane >> 2);
    int cchain = lane & 3;
    bool valid = n < N;

    int e = valid ? head4[(size_t)n * 4 + cchain] : -1;
    int cnt = 0;
    int lbase = tid * 33;
    while (e >= 0) {
        int nx = nexte[e];
        int u = packed[e];
        if (cnt < 32) {
            lbuf[lbase + cnt] = u;
        } else {
            nexte[e] = atomicExch(&ohead[n], e);   // nx already captured
        }
        cnt++;
        e = nx;
    }
    int cl = cnt < 32 ? cnt : 32;
    int base = lane & ~3;
    int c0 = __shfl(cl, base);
    int c1 = __shfl(cl, base + 1);
    int c2 = __shfl(cl, base + 2);
    int c3 = __shfl(cl, base + 3);
    int pc = (cchain > 0 ? c0 : 0) + (cchain > 1 ? c1 : 0) + (cchain > 2 ? c2 : 0);
    if (valid) {
        int* drow = slots + (size_t)n * ROWCAP + pc;
        for (int i = 0; i < cl; ++i) drow[i] = lbuf[lbase + i];
        if (cchain == 0) deg[n] = c0 + c1 + c2 + c3;
    }
}

// ---------------------------------------------------------------------------
// Gather over dense CSR rows: S[n] = sum h_b[src], cnt[n] packed type counts.
// One wave per node; row reads contiguous + independent, 8-wide unrolled.
// Overflow chain (never taken in practice) guarantees correctness.
// ---------------------------------------------------------------------------
__global__ __launch_bounds__(256) void gather_csr_kernel(
    const unsigned short* __restrict__ h_b,
    const int* __restrict__ deg, const int* __restrict__ slots,
    const int* __restrict__ ohead, const int* __restrict__ nexte,
    const int* __restrict__ packed,
    unsigned short* __restrict__ S_b, u64* __restrict__ cnt, int N)
{
    int n = blockIdx.x * 4 + (threadIdx.x >> 6);
    if (n >= N) return;
    int lane = threadIdx.x & 63;
    int m = deg[n];
    const int* row = slots + (size_t)n * ROWCAP;

    float ax = 0.f, ay = 0.f;
    u64 c = 0;
    int i = 0;
    for (; i + 8 <= m; i += 8) {
        int u0 = row[i + 0];
        int u1 = row[i + 1];
        int u2 = row[i + 2];
        int u3 = row[i + 3];
        int u4 = row[i + 4];
        int u5 = row[i + 5];
        int u6 = row[i + 6];
        int u7 = row[i + 7];
        u32 x0 = *((const u32*)(h_b + (size_t)(u0 & 0xffffff) * H) + lane);
        u32 x1 = *((const u32*)(h_b + (size_t)(u1 & 0xffffff) * H) + lane);
        u32 x2 = *((const u32*)(h_b + (size_t)(u2 & 0xffffff) * H) + lane);
        u32 x3 = *((const u32*)(h_b + (size_t)(u3 & 0xffffff) * H) + lane);
        u32 x4 = *((const u32*)(h_b + (size_t)(u4 & 0xffffff) * H) + lane);
        u32 x5 = *((const u32*)(h_b + (size_t)(u5 & 0xffffff) * H) + lane);
        u32 x6 = *((const u32*)(h_b + (size_t)(u6 & 0xffffff) * H) + lane);
        u32 x7 = *((const u32*)(h_b + (size_t)(u7 & 0xffffff) * H) + lane);
        c += (1ull << (7 * (u0 >> 24))) + (1ull << (7 * (u1 >> 24)))
           + (1ull << (7 * (u2 >> 24))) + (1ull << (7 * (u3 >> 24)))
           + (1ull << (7 * (u4 >> 24))) + (1ull << (7 * (u5 >> 24)))
           + (1ull << (7 * (u6 >> 24))) + (1ull << (7 * (u7 >> 24)));
        ax += bf_lo32(x0) + bf_lo32(x1) + bf_lo32(x2) + bf_lo32(x3)
            + bf_lo32(x4) + bf_lo32(x5) + bf_lo32(x6) + bf_lo32(x7);
        ay += bf_hi32(x0) + bf_hi32(x1) + bf_hi32(x2) + bf_hi32(x3)
            + bf_hi32(x4) + bf_hi32(x5) + bf_hi32(x6) + bf_hi32(x7);
    }
    for (; i + 4 <= m; i += 4) {
        int u0 = row[i + 0];
        int u1 = row[i + 1];
        int u2 = row[i + 2];
        int u3 = row[i + 3];
        u32 x0 = *((const u32*)(h_b + (size_t)(u0 & 0xffffff) * H) + lane);
        u32 x1 = *((const u32*)(h_b + (size_t)(u1 & 0xffffff) * H) + lane);
        u32 x2 = *((const u32*)(h_b + (size_t)(u2 & 0xffffff) * H) + lane);
        u32 x3 = *((const u32*)(h_b + (size_t)(u3 & 0xffffff) * H) + lane);
        c += (1ull << (7 * (u0 >> 24))) + (1ull << (7 * (u1 >> 24)))
           + (1ull << (7 * (u2 >> 24))) + (1ull << (7 * (u3 >> 24)));
        ax += bf_lo32(x0) + bf_lo32(x1) + bf_lo32(x2) + bf_lo32(x3);
        ay += bf_hi32(x0) + bf_hi32(x1) + bf_hi32(x2) + bf_hi32(x3);
    }
    for (; i < m; ++i) {
        int u = row[i];
        u32 x = *((const u32*)(h_b + (size_t)(u & 0xffffff) * H) + lane);
        c += 1ull << (7 * (u >> 24));
        ax += bf_lo32(x);
        ay += bf_hi32(x);
    }
    int oh = ohead[n];
    if (oh >= 0) {
        // overflow chain (essentially never taken; wave-uniform branch)
        int ecur = oh;
        while (ecur >= 0) {
            int u = packed[ecur];
            u32 x = *((const u32*)(h_b + (size_t)(u & 0xffffff) * H) + lane);
            c += 1ull << (7 * (u >> 24));
            ax += bf_lo32(x);
            ay += bf_hi32(x);
            ecur = nexte[ecur];
        }
    }
    u32 o = (u32)f2bf(ax) | ((u32)f2bf(ay) << 16);
    *((u32*)(S_b + (size_t)n * H) + lane) = o;
    if (lane == 0) cnt[n] = c;
}

// ---------------------------------------------------------------------------
// Fused GRU (MFMA). Block = (64-node tile) x (jhalf of 4 j-tiles); 4 waves,
// each wave owns ONE j-tile and loops 4 row-tiles (accs register-resident,
// weights loaded once per kc). Grid = 2x node-tiles (~1564 blocks) for
// latency hiding; LDS 39.9KB -> 4 resident blocks/CU. (r4-proven structure.)
//   aR = counts@embW_r + S@Wc_r^T + h@Whh_r^T    (gate-shared accumulators)
//   aZ = counts@embW_z + S@Wc_z^T + h@Whh_z^T
//   aIn = counts@embW_n + S@Wc_n^T ; aHn = h@Whh_n^T
// ---------------------------------------------------------------------------
__global__ __launch_bounds__(256, 4) void gru_mfma_kernel(
    const unsigned short* __restrict__ S_b, const unsigned short* __restrict__ h_b,
    const unsigned short* __restrict__ Wcs, const unsigned short* __restrict__ Whhs,
    const unsigned short* __restrict__ embWs,
    const float* __restrict__ bih, const float* __restrict__ bhh,
    const u64* __restrict__ cnt,
    const int* __restrict__ numn, float* __restrict__ out, int N)
{
    __shared__ unsigned short xs[64 * XS_STRIDE];    // 17408 B
    __shared__ unsigned short hsb[64 * XS_STRIDE];   // 17408 B
    __shared__ unsigned short cs[64 * CS_STRIDE];    //  5120 B

    int tid = threadIdx.x;
    int bx = blockIdx.x;
    int node0 = (bx >> 1) * 64;
    int jhalf = bx & 1;

    int lane = tid & 63;
    int wv = tid >> 6;
    int j = jhalf * 4 + wv;      // this wave's j-tile (0..7)

    // prefetch emb fragments (independent of staging; completes under barrier)
    short8 er = *(const short8*)(embWs + (size_t)((0 * 8 + j) * 64 + lane) * 8);
    short8 ez = *(const short8*)(embWs + (size_t)((1 * 8 + j) * 64 + lane) * 8);
    short8 en = *(const short8*)(embWs + (size_t)((2 * 8 + j) * 64 + lane) * 8);

    for (int c = tid; c < 1024; c += 256) {
        int r = c >> 4;
        int k8 = (c & 15) << 3;
        int n = node0 + r;
        int nc = n < N ? n : N - 1;
        *(short8*)(&xs[r * XS_STRIDE + k8]) =
            *(const short8*)(S_b + (size_t)nc * H + k8);
        *(short8*)(&hsb[r * XS_STRIDE + k8]) =
            *(const short8*)(h_b + (size_t)nc * H + k8);
    }
    {
        // counts tile: row r, type-group tg covers t = tg*8 .. tg*8+7 (t<9 live)
        int r = tid >> 2, tg = tid & 3;
        int n = node0 + r;
        u64 cv = cnt[n < N ? n : N - 1];
        short8 v = {0, 0, 0, 0, 0, 0, 0, 0};
        if (tg == 0) {
#pragma unroll
            for (int i = 0; i < 8; ++i)
                v[i] = (short)f2bf((float)((u32)(cv >> (7 * i)) & 127u));
        } else if (tg == 1) {
            v[0] = (short)f2bf((float)((u32)(cv >> 56) & 127u));
        }
        *(short8*)(&cs[r * CS_STRIDE + tg * 8]) = v;
    }
    __syncthreads();

    int am = lane & 15;
    int aq = lane >> 4;

    int num_nodes = numn[0];
    floatx4 zero = {0.f, 0.f, 0.f, 0.f};

    floatx4 aR[4], aZ[4], aIn[4], aHn[4];
#pragma unroll
    for (int rt = 0; rt < 4; ++rt) {
        short8 acn = *(const short8*)(&cs[(rt * 16 + am) * CS_STRIDE + aq * 8]);
        aR[rt]  = __builtin_amdgcn_mfma_f32_16x16x32_bf16(acn, er, zero, 0, 0, 0);
        aZ[rt]  = __builtin_amdgcn_mfma_f32_16x16x32_bf16(acn, ez, zero, 0, 0, 0);
        aIn[rt] = __builtin_amdgcn_mfma_f32_16x16x32_bf16(acn, en, zero, 0, 0, 0);
        aHn[rt] = zero;
    }
#pragma unroll
    for (int kc = 0; kc < 4; ++kc) {
        size_t c_r = (size_t)(((0 * 8 + j) * 4 + kc) * 64 + lane) * 8;
        size_t c_z = (size_t)(((1 * 8 + j) * 4 + kc) * 64 + lane) * 8;
        size_t c_n = (size_t)(((2 * 8 + j) * 4 + kc) * 64 + lane) * 8;
        short8 bir = *(const short8*)(Wcs + c_r);
        short8 bhr = *(const short8*)(Whhs + c_r);
        short8 biz = *(const short8*)(Wcs + c_z);
        short8 bhz = *(const short8*)(Whhs + c_z);
        short8 bin = *(const short8*)(Wcs + c_n);
        short8 bhn = *(const short8*)(Whhs + c_n);
#pragma unroll
        for (int rt = 0; rt < 4; ++rt) {
            int arow = rt * 16 + am;
            short8 axv = *(const short8*)(&xs[arow * XS_STRIDE + kc * 32 + aq * 8]);
            short8 ahv = *(const short8*)(&hsb[arow * XS_STRIDE + kc * 32 + aq * 8]);
            aR[rt]  = __builtin_amdgcn_mfma_f32_16x16x32_bf16(axv, bir, aR[rt], 0, 0, 0);
            aR[rt]  = __builtin_amdgcn_mfma_f32_16x16x32_bf16(ahv, bhr, aR[rt], 0, 0, 0);
            aZ[rt]  = __builtin_amdgcn_mfma_f32_16x16x32_bf16(axv, biz, aZ[rt], 0, 0, 0);
            aZ[rt]  = __builtin_amdgcn_mfma_f32_16x16x32_bf16(ahv, bhz, aZ[rt], 0, 0, 0);
            aIn[rt] = __builtin_amdgcn_mfma_f32_16x16x32_bf16(axv, bin, aIn[rt], 0, 0, 0);
            aHn[rt] = __builtin_amdgcn_mfma_f32_16x16x32_bf16(ahv, bhn, aHn[rt], 0, 0, 0);
        }
    }
    int c = j * 16 + am;
    float b_r = bih[c]       + bhh[c];
    float b_z = bih[128 + c] + bhh[128 + c];
    float b_in = bih[256 + c], b_hn = bhh[256 + c];
#pragma unroll
    for (int rt = 0; rt < 4; ++rt) {
#pragma unroll
        for (int q = 0; q < 4; ++q) {
            int m = rt * 16 + aq * 4 + q;
            int node = node0 + m;
            if (node < N) {
                float r  = sigmoid_f(aR[rt][q] + b_r);
                float z  = sigmoid_f(aZ[rt][q] + b_z);
                float nv = tanh_f((aIn[rt][q] + b_in) + r * (aHn[rt][q] + b_hn));
                float hv = bf2f(hsb[m * XS_STRIDE + c]);
                float o  = (1.0f - z) * nv + z * hv;
                out[(size_t)node * H + c] = (node < num_nodes) ? o : 0.0f;
            }
        }
    }
}

extern "C" void kernel_launch(void* const* d_in, const int* in_sizes, int n_in,
                              void* d_out, int out_size, void* d_ws, size_t ws_size,
                              hipStream_t stream) {
    const float* h    = (const float*)d_in[0];
    const int*  eidx  = (const int*)d_in[1];
    const int*  etype = (const int*)d_in[2];
    const int*  numn  = (const int*)d_in[3];
    const float* Wm   = (const float*)d_in[4];
    const float* bm   = (const float*)d_in[5];
    const float* emb  = (const float*)d_in[6];
    const float* Wih  = (const float*)d_in[7];
    const float* Whh  = (const float*)d_in[8];
    const float* bih  = (const float*)d_in[9];
    const float* bhh  = (const float*)d_in[10];

    int N = in_sizes[0] / H;
    int E = in_sizes[2];

    // ws layout:
    unsigned short* S_b   = (unsigned short*)d_ws;               // N*H bf16
    unsigned short* h_b   = S_b + (size_t)N * H;                 // N*H bf16
    unsigned short* Wcs   = h_b + (size_t)N * H;                 // 3*H*H (swizzled)
    unsigned short* Whhs  = Wcs + 3 * H * H;                     // 3*H*H (swizzled)
    unsigned short* embWs = Whhs + 3 * H * H;                    // 12288
    u64* cnt    = (u64*)(embWs + 12288);                         // N (8B-aligned)
    int* deg    = (int*)(cnt + N);                               // N
    int* ohead  = deg + N;                                       // N
    int* head4  = ohead + N;                                     // 4*N
    int* slots  = head4 + 4 * N;                                 // N*ROWCAP
    int* packed = slots + (size_t)N * ROWCAP;                    // E
    int* nexte  = packed + E;                                    // E

    int total8 = N * H / 8;
    int HB = (total8 + 255) / 256;
    int DB = (5 * N + 255) / 256;
    int PB = 264;
    fused_pre_kernel<<<HB + DB + PB, 256, 0, stream>>>(
        h, h_b, total8, head4, ohead, N, Wih, Whh, Wm, emb, bm,
        Wcs, Whhs, embWs, HB, DB);

    fill_ll_kernel<<<(E + 255) / 256, 256, 0, stream>>>(
        eidx, etype, head4, nexte, packed, E);

    ll2csr_kernel<<<(N + 63) / 64, 256, 0, stream>>>(
        head4, nexte, packed, slots, deg, ohead, N);

    gather_csr_kernel<<<(N + 3) / 4, 256, 0, stream>>>(
        h_b, deg, slots, ohead, nexte, packed, S_b, cnt, N);

    int nblk = ((N + 63) / 64) * 2;
    gru_mfma_kernel<<<nblk, 256, 0, stream>>>(S_b, h_b, Wcs, Whhs, embWs,
                                              bih, bhh, cnt, numn, (float*)d_out, N);
}

// Round 11
// 202.523 us; speedup vs baseline: 1.3154x; 1.0187x over previous
//
#include <hip/hip_runtime.h>
#include <math.h>

#define H 128
typedef unsigned int u32;
typedef unsigned long long u64;
typedef __attribute__((ext_vector_type(8))) short short8;
typedef __attribute__((ext_vector_type(4))) float floatx4;

#define XS_STRIDE 136   // bf16 elems per padded row (128 + 8) -> 272B
#define CS_STRIDE 40    // counts row stride (80B) -> conflict-free b128 reads
#define ROWCAP 48       // LDS row capacity per node (Poisson(12), max ~40)

__device__ __forceinline__ float sigmoid_f(float x) {
    return 1.0f / (1.0f + __expf(-x));
}
__device__ __forceinline__ float tanh_f(float x) {
    float t = __expf(-2.0f * fabsf(x));
    float r = (1.0f - t) / (1.0f + t);
    return copysignf(r, x);
}
// f32 -> bf16 bits, round-to-nearest-even (finite inputs)
__device__ __forceinline__ unsigned short f2bf(float x) {
    u32 u = __float_as_uint(x);
    return (unsigned short)((u + 0x7fffu + ((u >> 16) & 1u)) >> 16);
}
__device__ __forceinline__ float bf2f(unsigned short s) {
    return __uint_as_float(((u32)s) << 16);
}
__device__ __forceinline__ float bf_lo32(u32 u) { return __uint_as_float(u << 16); }
__device__ __forceinline__ float bf_hi32(u32 u) { return __uint_as_float(u & 0xffff0000u); }

// ---------------------------------------------------------------------------
// Fused pre-pass: [blocks 0..HB)   h (f32) -> h_b (bf16)
//                 [HB..HB+DB)      head4[]=-1 (4N)
//                 [HB+DB..)        weight prep (W_c fold, embW', Whh swizzle)
// Swizzle (B-frag, 16x16x32): frag[((gtile*4+kc)*64 + l)*8 + i] =
//   W[(gtile*16 + (l&15))][kc*32 + (l>>4)*8 + i]
// ---------------------------------------------------------------------------
__global__ __launch_bounds__(256) void fused_pre_kernel(
    const float* __restrict__ h, unsigned short* __restrict__ h_b, int total8,
    int* __restrict__ head4, int N,
    const float* __restrict__ Wih, const float* __restrict__ Whh,
    const float* __restrict__ Wm,  const float* __restrict__ emb,
    const float* __restrict__ bm,
    unsigned short* __restrict__ Wcs, unsigned short* __restrict__ Whhs,
    unsigned short* __restrict__ embWs, int HB, int DB)
{
    int b = blockIdx.x;
    if (b < HB) {
        int idx = b * 256 + threadIdx.x;
        if (idx >= total8) return;
        const float4* p = (const float4*)(h + (size_t)idx * 8);
        float4 a = p[0], bb = p[1];
        short8 v;
        v[0] = (short)f2bf(a.x);  v[1] = (short)f2bf(a.y);
        v[2] = (short)f2bf(a.z);  v[3] = (short)f2bf(a.w);
        v[4] = (short)f2bf(bb.x); v[5] = (short)f2bf(bb.y);
        v[6] = (short)f2bf(bb.z); v[7] = (short)f2bf(bb.w);
        *(short8*)(h_b + (size_t)idx * 8) = v;
        return;
    }
    if (b < HB + DB) {
        int idx = (b - HB) * 256 + threadIdx.x;
        if (idx < 4 * N) head4[idx] = -1;
        return;
    }
    int idx = (b - HB - DB) * 256 + threadIdx.x;
    if (idx < 49152) {
        // ---- W_c[g][k] = sum_c Wih[g][c] * Wm[c][k], f32 acc -> bf16 swizzled
        int g = idx >> 7;          // 0..383
        int k = idx & 127;
        float acc = 0.f;
#pragma unroll 4
        for (int c = 0; c < H; ++c)
            acc += Wih[(size_t)g * H + c] * Wm[(size_t)c * H + k];
        int gate = g >> 7;
        int wi = g & 127;
        int j = wi >> 4, m = wi & 15;
        int kc = k >> 5, q = (k >> 3) & 3, i = k & 7;
        int l = q * 16 + m;
        Wcs[(size_t)(((gate * 8 + j) * 4 + kc) * 64 + l) * 8 + i] = f2bf(acc);
    } else if (idx < 61440) {
        // ---- embW'[t][g] = sum_j (emb[t][j]+bm[j])*Wih[g][j], K=32 frag
        int s = idx - 49152;       // 0..12287
        int i = s & 7;
        int l = (s >> 3) & 63;
        int jb = s >> 9;           // gate*8 + j
        int gate = jb >> 3, jj = jb & 7;
        int q = l >> 4, m = l & 15;
        int t = q * 8 + i;         // edge type (K index)
        unsigned short v = 0;
        if (t < 9) {
            int g = gate * 128 + jj * 16 + m;
            float acc = 0.f;
#pragma unroll 4
            for (int jx = 0; jx < H; ++jx)
                acc += (emb[(size_t)t * H + jx] + bm[jx]) * Wih[(size_t)g * H + jx];
            v = f2bf(acc);
        }
        embWs[s] = v;
    } else if (idx < 67584) {
        // ---- Whh convert + swizzle
        int t2 = idx - 61440;      // 0..6143
        int l  = t2 & 63;
        int kc = (t2 >> 6) & 3;
        int jr = t2 >> 8;
        int m = l & 15, q = l >> 4;
        size_t srco = (size_t)(jr * 16 + m) * H + kc * 32 + q * 8;
        const float4* s0 = (const float4*)(Whh + srco);
        float4 a = s0[0], bb = s0[1];
        short8 v;
        v[0] = (short)f2bf(a.x);  v[1] = (short)f2bf(a.y);
        v[2] = (short)f2bf(a.z);  v[3] = (short)f2bf(a.w);
        v[4] = (short)f2bf(bb.x); v[5] = (short)f2bf(bb.y);
        v[6] = (short)f2bf(bb.z); v[7] = (short)f2bf(bb.w);
        *(short8*)(Whhs + (size_t)t2 * 8) = v;
    }
}

// ---------------------------------------------------------------------------
// Linked-list build (all writes coalesced by e; only a 4B atomicExch is
// random -- proven cheap in r6/r7/r10):
//   packed[e] = src | type<<24 ; nexte[e] = atomicExch(&head4[dst*4+(e&3)], e)
// ---------------------------------------------------------------------------
__global__ __launch_bounds__(256) void fill_ll_kernel(
    const int* __restrict__ eidx, const int* __restrict__ etype,
    int* __restrict__ head4, int* __restrict__ nexte,
    int* __restrict__ packed, int E)
{
    int e = blockIdx.x * 256 + threadIdx.x;
    if (e >= E) return;
    int src = eidx[e];
    int dst = eidx[E + e];
    int t = etype[e];
    t = t < 0 ? 0 : (t > 8 ? 8 : t);
    packed[e] = src | (t << 24);
    int old = atomicExch(&head4[(size_t)dst * 4 + (e & 3)], e);
    nexte[e] = old;
}

// ---------------------------------------------------------------------------
// Fused chase + gather (merges r10's ll2csr and gather; no CSR round-trip):
// Phase 1: 256 lanes chase 64 nodes x 4 sub-chains per-lane (independent,
//   ~3 hops each), pushing records into per-node LDS rows via LDS atomicAdd.
//   Row overflow (>48, P~1e-18) re-linked into an LDS overflow head; safe
//   across __syncthreads via same-CU L1 coherence (workgroup on one CU).
// Phase 2: each wave gathers 16 nodes from LDS rows (broadcast reads,
//   conflict-free); h-row loads 8-wide unrolled (independent, deep MLP).
// ---------------------------------------------------------------------------
__global__ __launch_bounds__(256) void gather_fused_kernel(
    const unsigned short* __restrict__ h_b,
    const int* __restrict__ head4, int* __restrict__ nexte,
    const int* __restrict__ packed,
    unsigned short* __restrict__ S_b, u64* __restrict__ cnt, int N)
{
    __shared__ int rowbuf[64 * ROWCAP];   // 12288 B
    __shared__ int lcnt[64];
    __shared__ int lohead[64];

    int tid = threadIdx.x;
    if (tid < 64) { lcnt[tid] = 0; lohead[tid] = -1; }
    __syncthreads();

    // ---- Phase 1: per-lane chain chase into LDS rows
    {
        int k = tid >> 2;              // node within block (0..63)
        int cch = tid & 3;             // sub-chain
        int n = blockIdx.x * 64 + k;
        if (n < N) {
            int e = head4[(size_t)n * 4 + cch];
            while (e >= 0) {
                int nx = nexte[e];
                int u = packed[e];
                int p = atomicAdd(&lcnt[k], 1);
                if (p < ROWCAP) {
                    rowbuf[k * ROWCAP + p] = u;
                } else {
                    nexte[e] = atomicExch(&lohead[k], e);
                }
                e = nx;
            }
        }
    }
    __syncthreads();

    // ---- Phase 2: wave-per-node gather from LDS rows
    int lane = tid & 63;
    int wv = tid >> 6;
    for (int t = 0; t < 16; ++t) {
        int kk = wv * 16 + t;
        int n = blockIdx.x * 64 + kk;
        if (n >= N) break;
        int m = lcnt[kk];
        m = m < ROWCAP ? m : ROWCAP;
        const int* row = &rowbuf[kk * ROWCAP];

        float ax = 0.f, ay = 0.f;
        u64 c = 0;
        int i = 0;
        for (; i + 8 <= m; i += 8) {
            int u0 = row[i + 0];
            int u1 = row[i + 1];
            int u2 = row[i + 2];
            int u3 = row[i + 3];
            int u4 = row[i + 4];
            int u5 = row[i + 5];
            int u6 = row[i + 6];
            int u7 = row[i + 7];
            u32 x0 = *((const u32*)(h_b + (size_t)(u0 & 0xffffff) * H) + lane);
            u32 x1 = *((const u32*)(h_b + (size_t)(u1 & 0xffffff) * H) + lane);
            u32 x2 = *((const u32*)(h_b + (size_t)(u2 & 0xffffff) * H) + lane);
            u32 x3 = *((const u32*)(h_b + (size_t)(u3 & 0xffffff) * H) + lane);
            u32 x4 = *((const u32*)(h_b + (size_t)(u4 & 0xffffff) * H) + lane);
            u32 x5 = *((const u32*)(h_b + (size_t)(u5 & 0xffffff) * H) + lane);
            u32 x6 = *((const u32*)(h_b + (size_t)(u6 & 0xffffff) * H) + lane);
            u32 x7 = *((const u32*)(h_b + (size_t)(u7 & 0xffffff) * H) + lane);
            c += (1ull << (7 * (u0 >> 24))) + (1ull << (7 * (u1 >> 24)))
               + (1ull << (7 * (u2 >> 24))) + (1ull << (7 * (u3 >> 24)))
               + (1ull << (7 * (u4 >> 24))) + (1ull << (7 * (u5 >> 24)))
               + (1ull << (7 * (u6 >> 24))) + (1ull << (7 * (u7 >> 24)));
            ax += bf_lo32(x0) + bf_lo32(x1) + bf_lo32(x2) + bf_lo32(x3)
                + bf_lo32(x4) + bf_lo32(x5) + bf_lo32(x6) + bf_lo32(x7);
            ay += bf_hi32(x0) + bf_hi32(x1) + bf_hi32(x2) + bf_hi32(x3)
                + bf_hi32(x4) + bf_hi32(x5) + bf_hi32(x6) + bf_hi32(x7);
        }
        for (; i + 4 <= m; i += 4) {
            int u0 = row[i + 0];
            int u1 = row[i + 1];
            int u2 = row[i + 2];
            int u3 = row[i + 3];
            u32 x0 = *((const u32*)(h_b + (size_t)(u0 & 0xffffff) * H) + lane);
            u32 x1 = *((const u32*)(h_b + (size_t)(u1 & 0xffffff) * H) + lane);
            u32 x2 = *((const u32*)(h_b + (size_t)(u2 & 0xffffff) * H) + lane);
            u32 x3 = *((const u32*)(h_b + (size_t)(u3 & 0xffffff) * H) + lane);
            c += (1ull << (7 * (u0 >> 24))) + (1ull << (7 * (u1 >> 24)))
               + (1ull << (7 * (u2 >> 24))) + (1ull << (7 * (u3 >> 24)));
            ax += bf_lo32(x0) + bf_lo32(x1) + bf_lo32(x2) + bf_lo32(x3);
            ay += bf_hi32(x0) + bf_hi32(x1) + bf_hi32(x2) + bf_hi32(x3);
        }
        for (; i < m; ++i) {
            int u = row[i];
            u32 x = *((const u32*)(h_b + (size_t)(u & 0xffffff) * H) + lane);
            c += 1ull << (7 * (u >> 24));
            ax += bf_lo32(x);
            ay += bf_hi32(x);
        }
        int oh = lohead[kk];
        if (oh >= 0) {
            // overflow chain (essentially never taken; wave-uniform branch)
            int ecur = oh;
            while (ecur >= 0) {
                int u = packed[ecur];
                u32 x = *((const u32*)(h_b + (size_t)(u & 0xffffff) * H) + lane);
                c += 1ull << (7 * (u >> 24));
                ax += bf_lo32(x);
                ay += bf_hi32(x);
                ecur = nexte[ecur];
            }
        }
        u32 o = (u32)f2bf(ax) | ((u32)f2bf(ay) << 16);
        *((u32*)(S_b + (size_t)n * H) + lane) = o;
        if (lane == 0) cnt[n] = c;
    }
}

// ---------------------------------------------------------------------------
// Fused GRU (MFMA). Block = (64-node tile) x (jhalf of 4 j-tiles); 4 waves,
// each wave owns ONE j-tile and loops 4 row-tiles (accs register-resident,
// weights loaded once per kc). Grid = 2x node-tiles (~1564 blocks) for
// latency hiding; LDS 39.9KB -> 4 resident blocks/CU. (r4-proven structure.)
//   aR = counts@embW_r + S@Wc_r^T + h@Whh_r^T    (gate-shared accumulators)
//   aZ = counts@embW_z + S@Wc_z^T + h@Whh_z^T
//   aIn = counts@embW_n + S@Wc_n^T ; aHn = h@Whh_n^T
// ---------------------------------------------------------------------------
__global__ __launch_bounds__(256, 4) void gru_mfma_kernel(
    const unsigned short* __restrict__ S_b, const unsigned short* __restrict__ h_b,
    const unsigned short* __restrict__ Wcs, const unsigned short* __restrict__ Whhs,
    const unsigned short* __restrict__ embWs,
    const float* __restrict__ bih, const float* __restrict__ bhh,
    const u64* __restrict__ cnt,
    const int* __restrict__ numn, float* __restrict__ out, int N)
{
    __shared__ unsigned short xs[64 * XS_STRIDE];    // 17408 B
    __shared__ unsigned short hsb[64 * XS_STRIDE];   // 17408 B
    __shared__ unsigned short cs[64 * CS_STRIDE];    //  5120 B

    int tid = threadIdx.x;
    int bx = blockIdx.x;
    int node0 = (bx >> 1) * 64;
    int jhalf = bx & 1;

    int lane = tid & 63;
    int wv = tid >> 6;
    int j = jhalf * 4 + wv;      // this wave's j-tile (0..7)

    // prefetch emb fragments (independent of staging; completes under barrier)
    short8 er = *(const short8*)(embWs + (size_t)((0 * 8 + j) * 64 + lane) * 8);
    short8 ez = *(const short8*)(embWs + (size_t)((1 * 8 + j) * 64 + lane) * 8);
    short8 en = *(const short8*)(embWs + (size_t)((2 * 8 + j) * 64 + lane) * 8);

    for (int c = tid; c < 1024; c += 256) {
        int r = c >> 4;
        int k8 = (c & 15) << 3;
        int n = node0 + r;
        int nc = n < N ? n : N - 1;
        *(short8*)(&xs[r * XS_STRIDE + k8]) =
            *(const short8*)(S_b + (size_t)nc * H + k8);
        *(short8*)(&hsb[r * XS_STRIDE + k8]) =
            *(const short8*)(h_b + (size_t)nc * H + k8);
    }
    {
        // counts tile: row r, type-group tg covers t = tg*8 .. tg*8+7 (t<9 live)
        int r = tid >> 2, tg = tid & 3;
        int n = node0 + r;
        u64 cv = cnt[n < N ? n : N - 1];
        short8 v = {0, 0, 0, 0, 0, 0, 0, 0};
        if (tg == 0) {
#pragma unroll
            for (int i = 0; i < 8; ++i)
                v[i] = (short)f2bf((float)((u32)(cv >> (7 * i)) & 127u));
        } else if (tg == 1) {
            v[0] = (short)f2bf((float)((u32)(cv >> 56) & 127u));
        }
        *(short8*)(&cs[r * CS_STRIDE + tg * 8]) = v;
    }
    __syncthreads();

    int am = lane & 15;
    int aq = lane >> 4;

    int num_nodes = numn[0];
    floatx4 zero = {0.f, 0.f, 0.f, 0.f};

    floatx4 aR[4], aZ[4], aIn[4], aHn[4];
#pragma unroll
    for (int rt = 0; rt < 4; ++rt) {
        short8 acn = *(const short8*)(&cs[(rt * 16 + am) * CS_STRIDE + aq * 8]);
        aR[rt]  = __builtin_amdgcn_mfma_f32_16x16x32_bf16(acn, er, zero, 0, 0, 0);
        aZ[rt]  = __builtin_amdgcn_mfma_f32_16x16x32_bf16(acn, ez, zero, 0, 0, 0);
        aIn[rt] = __builtin_amdgcn_mfma_f32_16x16x32_bf16(acn, en, zero, 0, 0, 0);
        aHn[rt] = zero;
    }
#pragma unroll
    for (int kc = 0; kc < 4; ++kc) {
        size_t c_r = (size_t)(((0 * 8 + j) * 4 + kc) * 64 + lane) * 8;
        size_t c_z = (size_t)(((1 * 8 + j) * 4 + kc) * 64 + lane) * 8;
        size_t c_n = (size_t)(((2 * 8 + j) * 4 + kc) * 64 + lane) * 8;
        short8 bir = *(const short8*)(Wcs + c_r);
        short8 bhr = *(const short8*)(Whhs + c_r);
        short8 biz = *(const short8*)(Wcs + c_z);
        short8 bhz = *(const short8*)(Whhs + c_z);
        short8 bin = *(const short8*)(Wcs + c_n);
        short8 bhn = *(const short8*)(Whhs + c_n);
#pragma unroll
        for (int rt = 0; rt < 4; ++rt) {
            int arow = rt * 16 + am;
            short8 axv = *(const short8*)(&xs[arow * XS_STRIDE + kc * 32 + aq * 8]);
            short8 ahv = *(const short8*)(&hsb[arow * XS_STRIDE + kc * 32 + aq * 8]);
            aR[rt]  = __builtin_amdgcn_mfma_f32_16x16x32_bf16(axv, bir, aR[rt], 0, 0, 0);
            aR[rt]  = __builtin_amdgcn_mfma_f32_16x16x32_bf16(ahv, bhr, aR[rt], 0, 0, 0);
            aZ[rt]  = __builtin_amdgcn_mfma_f32_16x16x32_bf16(axv, biz, aZ[rt], 0, 0, 0);
            aZ[rt]  = __builtin_amdgcn_mfma_f32_16x16x32_bf16(ahv, bhz, aZ[rt], 0, 0, 0);
            aIn[rt] = __builtin_amdgcn_mfma_f32_16x16x32_bf16(axv, bin, aIn[rt], 0, 0, 0);
            aHn[rt] = __builtin_amdgcn_mfma_f32_16x16x32_bf16(ahv, bhn, aHn[rt], 0, 0, 0);
        }
    }
    int c = j * 16 + am;
    float b_r = bih[c]       + bhh[c];
    float b_z = bih[128 + c] + bhh[128 + c];
    float b_in = bih[256 + c], b_hn = bhh[256 + c];
#pragma unroll
    for (int rt = 0; rt < 4; ++rt) {
#pragma unroll
        for (int q = 0; q < 4; ++q) {
            int m = rt * 16 + aq * 4 + q;
            int node = node0 + m;
            if (node < N) {
                float r  = sigmoid_f(aR[rt][q] + b_r);
                float z  = sigmoid_f(aZ[rt][q] + b_z);
                float nv = tanh_f((aIn[rt][q] + b_in) + r * (aHn[rt][q] + b_hn));
                float hv = bf2f(hsb[m * XS_STRIDE + c]);
                float o  = (1.0f - z) * nv + z * hv;
                out[(size_t)node * H + c] = (node < num_nodes) ? o : 0.0f;
            }
        }
    }
}

extern "C" void kernel_launch(void* const* d_in, const int* in_sizes, int n_in,
                              void* d_out, int out_size, void* d_ws, size_t ws_size,
                              hipStream_t stream) {
    const float* h    = (const float*)d_in[0];
    const int*  eidx  = (const int*)d_in[1];
    const int*  etype = (const int*)d_in[2];
    const int*  numn  = (const int*)d_in[3];
    const float* Wm   = (const float*)d_in[4];
    const float* bm   = (const float*)d_in[5];
    const float* emb  = (const float*)d_in[6];
    const float* Wih  = (const float*)d_in[7];
    const float* Whh  = (const float*)d_in[8];
    const float* bih  = (const float*)d_in[9];
    const float* bhh  = (const float*)d_in[10];

    int N = in_sizes[0] / H;
    int E = in_sizes[2];

    // ws layout:
    unsigned short* S_b   = (unsigned short*)d_ws;               // N*H bf16
    unsigned short* h_b   = S_b + (size_t)N * H;                 // N*H bf16
    unsigned short* Wcs   = h_b + (size_t)N * H;                 // 3*H*H (swizzled)
    unsigned short* Whhs  = Wcs + 3 * H * H;                     // 3*H*H (swizzled)
    unsigned short* embWs = Whhs + 3 * H * H;                    // 12288
    u64* cnt    = (u64*)(embWs + 12288);                         // N (8B-aligned)
    int* head4  = (int*)(cnt + N);                               // 4*N
    int* packed = head4 + 4 * N;                                 // E
    int* nexte  = packed + E;                                    // E

    int total8 = N * H / 8;
    int HB = (total8 + 255) / 256;
    int DB = (4 * N + 255) / 256;
    int PB = 264;
    fused_pre_kernel<<<HB + DB + PB, 256, 0, stream>>>(
        h, h_b, total8, head4, N, Wih, Whh, Wm, emb, bm,
        Wcs, Whhs, embWs, HB, DB);

    fill_ll_kernel<<<(E + 255) / 256, 256, 0, stream>>>(
        eidx, etype, head4, nexte, packed, E);

    gather_fused_kernel<<<(N + 63) / 64, 256, 0, stream>>>(
        h_b, head4, nexte, packed, S_b, cnt, N);

    int nblk = ((N + 63) / 64) * 2;
    gru_mfma_kernel<<<nblk, 256, 0, stream>>>(S_b, h_b, Wcs, Whhs, embWs,
                                              bih, bhh, cnt, numn, (float*)d_out, N);
}

// Round 12
// 198.849 us; speedup vs baseline: 1.3397x; 1.0185x over previous
//
#include <hip/hip_runtime.h>
#include <math.h>

#define H 128
typedef unsigned int u32;
typedef unsigned long long u64;
typedef __attribute__((ext_vector_type(8))) short short8;
typedef __attribute__((ext_vector_type(4))) float floatx4;

#define XS_STRIDE 136   // bf16 elems per padded row (128 + 8) -> 272B
#define CS_STRIDE 40    // counts row stride (80B) -> conflict-free b128 reads
#define ROWCAP 48       // LDS row capacity per node (Poisson(12), max ~40)

__device__ __forceinline__ float sigmoid_f(float x) {
    return 1.0f / (1.0f + __expf(-x));
}
__device__ __forceinline__ float tanh_f(float x) {
    float t = __expf(-2.0f * fabsf(x));
    float r = (1.0f - t) / (1.0f + t);
    return copysignf(r, x);
}
// f32 -> bf16 bits, round-to-nearest-even (finite inputs)
__device__ __forceinline__ unsigned short f2bf(float x) {
    u32 u = __float_as_uint(x);
    return (unsigned short)((u + 0x7fffu + ((u >> 16) & 1u)) >> 16);
}
__device__ __forceinline__ float bf2f(unsigned short s) {
    return __uint_as_float(((u32)s) << 16);
}
__device__ __forceinline__ float bf_lo32(u32 u) { return __uint_as_float(u << 16); }
__device__ __forceinline__ float bf_hi32(u32 u) { return __uint_as_float(u & 0xffff0000u); }

// ---------------------------------------------------------------------------
// Fused pre-pass: [blocks 0..HB)   h (f32) -> h_b (bf16)
//                 [HB..HB+DB)      head4[]=-1 (4N)
//                 [HB+DB..)        weight prep (W_c fold, embW', Whh swizzle)
// Swizzle (B-frag, 16x16x32): frag[((gtile*4+kc)*64 + l)*8 + i] =
//   W[(gtile*16 + (l&15))][kc*32 + (l>>4)*8 + i]
// ---------------------------------------------------------------------------
__global__ __launch_bounds__(256) void fused_pre_kernel(
    const float* __restrict__ h, unsigned short* __restrict__ h_b, int total8,
    int* __restrict__ head4, int N,
    const float* __restrict__ Wih, const float* __restrict__ Whh,
    const float* __restrict__ Wm,  const float* __restrict__ emb,
    const float* __restrict__ bm,
    unsigned short* __restrict__ Wcs, unsigned short* __restrict__ Whhs,
    unsigned short* __restrict__ embWs, int HB, int DB)
{
    int b = blockIdx.x;
    if (b < HB) {
        int idx = b * 256 + threadIdx.x;
        if (idx >= total8) return;
        const float4* p = (const float4*)(h + (size_t)idx * 8);
        float4 a = p[0], bb = p[1];
        short8 v;
        v[0] = (short)f2bf(a.x);  v[1] = (short)f2bf(a.y);
        v[2] = (short)f2bf(a.z);  v[3] = (short)f2bf(a.w);
        v[4] = (short)f2bf(bb.x); v[5] = (short)f2bf(bb.y);
        v[6] = (short)f2bf(bb.z); v[7] = (short)f2bf(bb.w);
        *(short8*)(h_b + (size_t)idx * 8) = v;
        return;
    }
    if (b < HB + DB) {
        int idx = (b - HB) * 256 + threadIdx.x;
        if (idx < 4 * N) head4[idx] = -1;
        return;
    }
    int idx = (b - HB - DB) * 256 + threadIdx.x;
    if (idx < 49152) {
        // ---- W_c[g][k] = sum_c Wih[g][c] * Wm[c][k], f32 acc -> bf16 swizzled
        int g = idx >> 7;          // 0..383
        int k = idx & 127;
        float acc = 0.f;
#pragma unroll 4
        for (int c = 0; c < H; ++c)
            acc += Wih[(size_t)g * H + c] * Wm[(size_t)c * H + k];
        int gate = g >> 7;
        int wi = g & 127;
        int j = wi >> 4, m = wi & 15;
        int kc = k >> 5, q = (k >> 3) & 3, i = k & 7;
        int l = q * 16 + m;
        Wcs[(size_t)(((gate * 8 + j) * 4 + kc) * 64 + l) * 8 + i] = f2bf(acc);
    } else if (idx < 61440) {
        // ---- embW'[t][g] = sum_j (emb[t][j]+bm[j])*Wih[g][j], K=32 frag
        int s = idx - 49152;       // 0..12287
        int i = s & 7;
        int l = (s >> 3) & 63;
        int jb = s >> 9;           // gate*8 + j
        int gate = jb >> 3, jj = jb & 7;
        int q = l >> 4, m = l & 15;
        int t = q * 8 + i;         // edge type (K index)
        unsigned short v = 0;
        if (t < 9) {
            int g = gate * 128 + jj * 16 + m;
            float acc = 0.f;
#pragma unroll 4
            for (int jx = 0; jx < H; ++jx)
                acc += (emb[(size_t)t * H + jx] + bm[jx]) * Wih[(size_t)g * H + jx];
            v = f2bf(acc);
        }
        embWs[s] = v;
    } else if (idx < 67584) {
        // ---- Whh convert + swizzle
        int t2 = idx - 61440;      // 0..6143
        int l  = t2 & 63;
        int kc = (t2 >> 6) & 3;
        int jr = t2 >> 8;
        int m = l & 15, q = l >> 4;
        size_t srco = (size_t)(jr * 16 + m) * H + kc * 32 + q * 8;
        const float4* s0 = (const float4*)(Whh + srco);
        float4 a = s0[0], bb = s0[1];
        short8 v;
        v[0] = (short)f2bf(a.x);  v[1] = (short)f2bf(a.y);
        v[2] = (short)f2bf(a.z);  v[3] = (short)f2bf(a.w);
        v[4] = (short)f2bf(bb.x); v[5] = (short)f2bf(bb.y);
        v[6] = (short)f2bf(bb.z); v[7] = (short)f2bf(bb.w);
        *(short8*)(Whhs + (size_t)t2 * 8) = v;
    }
}

// ---------------------------------------------------------------------------
// Linked-list build (all writes coalesced by e; only a 4B atomicExch is
// random -- proven cheap in r6/r7/r10/r11):
//   packed[e] = src | type<<24 ; nexte[e] = atomicExch(&head4[dst*4+(e&3)], e)
// ---------------------------------------------------------------------------
__global__ __launch_bounds__(256) void fill_ll_kernel(
    const int* __restrict__ eidx, const int* __restrict__ etype,
    int* __restrict__ head4, int* __restrict__ nexte,
    int* __restrict__ packed, int E)
{
    int e = blockIdx.x * 256 + threadIdx.x;
    if (e >= E) return;
    int src = eidx[e];
    int dst = eidx[E + e];
    int t = etype[e];
    t = t < 0 ? 0 : (t > 8 ? 8 : t);
    packed[e] = src | (t << 24);
    int old = atomicExch(&head4[(size_t)dst * 4 + (e & 3)], e);
    nexte[e] = old;
}

// ---------------------------------------------------------------------------
// FUSED chase + gather + GRU (one block = 64 nodes, 512 threads / 8 waves).
// No global S_b / cnt round-trip, one fewer dispatch.
//  Phase 1 (overlapped): tid<256 chase 64 nodes x 4 sub-chains into rowbuf
//    (LDS atomicAdd append; overflow -> LDS lohead, P~1e-18), WHILE
//    tid>=256 stage the 64-node h-tile into hsb (BW hides under chase).
//  Phase 2: each wave gathers 8 nodes from LDS rows (8-wide unrolled h-row
//    loads), writing S (bf16) straight into xs and counts into cs.
//  Phase 3: GRU, r4-proven wave structure: wave w owns j-tile w (8 waves =
//    8 j-tiles), loops 4 row-tiles; weights loaded once per (j,kc).
//   aR = counts@embW_r + S@Wc_r^T + h@Whh_r^T    (gate-shared accumulators)
//   aZ = counts@embW_z + S@Wc_z^T + h@Whh_z^T
//   aIn = counts@embW_n + S@Wc_n^T ; aHn = h@Whh_n^T
// LDS 52.3 KB; __launch_bounds__(512,4) -> 2 blocks/CU (16 waves), VGPR<=128.
// ---------------------------------------------------------------------------
__global__ __launch_bounds__(512, 4) void gather_gru_kernel(
    const unsigned short* __restrict__ h_b,
    const int* __restrict__ head4, int* __restrict__ nexte,
    const int* __restrict__ packed,
    const unsigned short* __restrict__ Wcs, const unsigned short* __restrict__ Whhs,
    const unsigned short* __restrict__ embWs,
    const float* __restrict__ bih, const float* __restrict__ bhh,
    const int* __restrict__ numn, float* __restrict__ out, int N)
{
    __shared__ unsigned short xs[64 * XS_STRIDE];    // 17408 B (S tile, bf16)
    __shared__ unsigned short hsb[64 * XS_STRIDE];   // 17408 B (h tile, bf16)
    __shared__ unsigned short cs[64 * CS_STRIDE];    //  5120 B (counts tile)
    __shared__ int rowbuf[64 * ROWCAP];              // 12288 B (edge records)
    __shared__ int lcnt[64];
    __shared__ int lohead[64];

    int tid = threadIdx.x;
    int node0 = blockIdx.x * 64;
    int lane = tid & 63;
    int wv = tid >> 6;           // 0..7
    int j = wv;                  // this wave's j-tile

    // emb fragments prefetch (consumed in phase 3; independent of everything)
    short8 er = *(const short8*)(embWs + (size_t)((0 * 8 + j) * 64 + lane) * 8);
    short8 ez = *(const short8*)(embWs + (size_t)((1 * 8 + j) * 64 + lane) * 8);
    short8 en = *(const short8*)(embWs + (size_t)((2 * 8 + j) * 64 + lane) * 8);

    if (tid < 64) { lcnt[tid] = 0; lohead[tid] = -1; }
    __syncthreads();

    // ---- Phase 1: chase (tid<256)  ||  h-tile staging (tid>=256)
    if (tid < 256) {
        int k = tid >> 2;              // node within block (0..63)
        int cch = tid & 3;             // sub-chain
        int n = node0 + k;
        if (n < N) {
            int e = head4[(size_t)n * 4 + cch];
            while (e >= 0) {
                int nx = nexte[e];
                int u = packed[e];
                int p = atomicAdd(&lcnt[k], 1);
                if (p < ROWCAP) {
                    rowbuf[k * ROWCAP + p] = u;
                } else {
                    nexte[e] = atomicExch(&lohead[k], e);
                }
                e = nx;
            }
        }
    } else {
        int idx = tid - 256;           // 0..255, 4 chunks each of 1024
#pragma unroll
        for (int q = 0; q < 4; ++q) {
            int c = idx * 4 + q;
            int r = c >> 4;
            int k8 = (c & 15) << 3;
            int n = node0 + r;
            int nc = n < N ? n : N - 1;
            *(short8*)(&hsb[r * XS_STRIDE + k8]) =
                *(const short8*)(h_b + (size_t)nc * H + k8);
        }
    }
    __syncthreads();

    // ---- Phase 2: wave-per-8-nodes gather from LDS rows -> xs / cs
    for (int tt = 0; tt < 8; ++tt) {
        int kk = wv * 8 + tt;
        int n = node0 + kk;
        if (n < N) {
            int m = lcnt[kk];
            m = m < ROWCAP ? m : ROWCAP;
            const int* row = &rowbuf[kk * ROWCAP];

            float ax = 0.f, ay = 0.f;
            u64 c = 0;
            int i = 0;
            for (; i + 8 <= m; i += 8) {
                int u0 = row[i + 0];
                int u1 = row[i + 1];
                int u2 = row[i + 2];
                int u3 = row[i + 3];
                int u4 = row[i + 4];
                int u5 = row[i + 5];
                int u6 = row[i + 6];
                int u7 = row[i + 7];
                u32 x0 = *((const u32*)(h_b + (size_t)(u0 & 0xffffff) * H) + lane);
                u32 x1 = *((const u32*)(h_b + (size_t)(u1 & 0xffffff) * H) + lane);
                u32 x2 = *((const u32*)(h_b + (size_t)(u2 & 0xffffff) * H) + lane);
                u32 x3 = *((const u32*)(h_b + (size_t)(u3 & 0xffffff) * H) + lane);
                u32 x4 = *((const u32*)(h_b + (size_t)(u4 & 0xffffff) * H) + lane);
                u32 x5 = *((const u32*)(h_b + (size_t)(u5 & 0xffffff) * H) + lane);
                u32 x6 = *((const u32*)(h_b + (size_t)(u6 & 0xffffff) * H) + lane);
                u32 x7 = *((const u32*)(h_b + (size_t)(u7 & 0xffffff) * H) + lane);
                c += (1ull << (7 * (u0 >> 24))) + (1ull << (7 * (u1 >> 24)))
                   + (1ull << (7 * (u2 >> 24))) + (1ull << (7 * (u3 >> 24)))
                   + (1ull << (7 * (u4 >> 24))) + (1ull << (7 * (u5 >> 24)))
                   + (1ull << (7 * (u6 >> 24))) + (1ull << (7 * (u7 >> 24)));
                ax += bf_lo32(x0) + bf_lo32(x1) + bf_lo32(x2) + bf_lo32(x3)
                    + bf_lo32(x4) + bf_lo32(x5) + bf_lo32(x6) + bf_lo32(x7);
                ay += bf_hi32(x0) + bf_hi32(x1) + bf_hi32(x2) + bf_hi32(x3)
                    + bf_hi32(x4) + bf_hi32(x5) + bf_hi32(x6) + bf_hi32(x7);
            }
            for (; i + 4 <= m; i += 4) {
                int u0 = row[i + 0];
                int u1 = row[i + 1];
                int u2 = row[i + 2];
                int u3 = row[i + 3];
                u32 x0 = *((const u32*)(h_b + (size_t)(u0 & 0xffffff) * H) + lane);
                u32 x1 = *((const u32*)(h_b + (size_t)(u1 & 0xffffff) * H) + lane);
                u32 x2 = *((const u32*)(h_b + (size_t)(u2 & 0xffffff) * H) + lane);
                u32 x3 = *((const u32*)(h_b + (size_t)(u3 & 0xffffff) * H) + lane);
                c += (1ull << (7 * (u0 >> 24))) + (1ull << (7 * (u1 >> 24)))
                   + (1ull << (7 * (u2 >> 24))) + (1ull << (7 * (u3 >> 24)));
                ax += bf_lo32(x0) + bf_lo32(x1) + bf_lo32(x2) + bf_lo32(x3);
                ay += bf_hi32(x0) + bf_hi32(x1) + bf_hi32(x2) + bf_hi32(x3);
            }
            for (; i < m; ++i) {
                int u = row[i];
                u32 x = *((const u32*)(h_b + (size_t)(u & 0xffffff) * H) + lane);
                c += 1ull << (7 * (u >> 24));
                ax += bf_lo32(x);
                ay += bf_hi32(x);
            }
            int oh = lohead[kk];
            if (oh >= 0) {
                // overflow chain (essentially never; wave-uniform branch)
                int ecur = oh;
                while (ecur >= 0) {
                    int u = packed[ecur];
                    u32 x = *((const u32*)(h_b + (size_t)(u & 0xffffff) * H) + lane);
                    c += 1ull << (7 * (u >> 24));
                    ax += bf_lo32(x);
                    ay += bf_hi32(x);
                    ecur = nexte[ecur];
                }
            }
            u32 o = (u32)f2bf(ax) | ((u32)f2bf(ay) << 16);
            ((u32*)&xs[kk * XS_STRIDE])[lane] = o;
            if (lane < 32)
                cs[kk * CS_STRIDE + lane] =
                    (lane < 9) ? f2bf((float)((u32)(c >> (7 * lane)) & 127u))
                               : (unsigned short)0;
        }
    }
    __syncthreads();

    // ---- Phase 3: GRU (wave j = wv, 4 row-tiles)
    int am = lane & 15;
    int aq = lane >> 4;
    int num_nodes = numn[0];
    floatx4 zero = {0.f, 0.f, 0.f, 0.f};

    floatx4 aR[4], aZ[4], aIn[4], aHn[4];
#pragma unroll
    for (int rt = 0; rt < 4; ++rt) {
        short8 acn = *(const short8*)(&cs[(rt * 16 + am) * CS_STRIDE + aq * 8]);
        aR[rt]  = __builtin_amdgcn_mfma_f32_16x16x32_bf16(acn, er, zero, 0, 0, 0);
        aZ[rt]  = __builtin_amdgcn_mfma_f32_16x16x32_bf16(acn, ez, zero, 0, 0, 0);
        aIn[rt] = __builtin_amdgcn_mfma_f32_16x16x32_bf16(acn, en, zero, 0, 0, 0);
        aHn[rt] = zero;
    }
#pragma unroll
    for (int kc = 0; kc < 4; ++kc) {
        size_t c_r = (size_t)(((0 * 8 + j) * 4 + kc) * 64 + lane) * 8;
        size_t c_z = (size_t)(((1 * 8 + j) * 4 + kc) * 64 + lane) * 8;
        size_t c_n = (size_t)(((2 * 8 + j) * 4 + kc) * 64 + lane) * 8;
        short8 bir = *(const short8*)(Wcs + c_r);
        short8 bhr = *(const short8*)(Whhs + c_r);
        short8 biz = *(const short8*)(Wcs + c_z);
        short8 bhz = *(const short8*)(Whhs + c_z);
        short8 bin = *(const short8*)(Wcs + c_n);
        short8 bhn = *(const short8*)(Whhs + c_n);
#pragma unroll
        for (int rt = 0; rt < 4; ++rt) {
            int arow = rt * 16 + am;
            short8 axv = *(const short8*)(&xs[arow * XS_STRIDE + kc * 32 + aq * 8]);
            short8 ahv = *(const short8*)(&hsb[arow * XS_STRIDE + kc * 32 + aq * 8]);
            aR[rt]  = __builtin_amdgcn_mfma_f32_16x16x32_bf16(axv, bir, aR[rt], 0, 0, 0);
            aR[rt]  = __builtin_amdgcn_mfma_f32_16x16x32_bf16(ahv, bhr, aR[rt], 0, 0, 0);
            aZ[rt]  = __builtin_amdgcn_mfma_f32_16x16x32_bf16(axv, biz, aZ[rt], 0, 0, 0);
            aZ[rt]  = __builtin_amdgcn_mfma_f32_16x16x32_bf16(ahv, bhz, aZ[rt], 0, 0, 0);
            aIn[rt] = __builtin_amdgcn_mfma_f32_16x16x32_bf16(axv, bin, aIn[rt], 0, 0, 0);
            aHn[rt] = __builtin_amdgcn_mfma_f32_16x16x32_bf16(ahv, bhn, aHn[rt], 0, 0, 0);
        }
    }
    int c = j * 16 + am;
    float b_r = bih[c]       + bhh[c];
    float b_z = bih[128 + c] + bhh[128 + c];
    float b_in = bih[256 + c], b_hn = bhh[256 + c];
#pragma unroll
    for (int rt = 0; rt < 4; ++rt) {
#pragma unroll
        for (int q = 0; q < 4; ++q) {
            int m = rt * 16 + aq * 4 + q;
            int node = node0 + m;
            if (node < N) {
                float r  = sigmoid_f(aR[rt][q] + b_r);
                float z  = sigmoid_f(aZ[rt][q] + b_z);
                float nv = tanh_f((aIn[rt][q] + b_in) + r * (aHn[rt][q] + b_hn));
                float hv = bf2f(hsb[m * XS_STRIDE + c]);
                float o  = (1.0f - z) * nv + z * hv;
                out[(size_t)node * H + c] = (node < num_nodes) ? o : 0.0f;
            }
        }
    }
}

extern "C" void kernel_launch(void* const* d_in, const int* in_sizes, int n_in,
                              void* d_out, int out_size, void* d_ws, size_t ws_size,
                              hipStream_t stream) {
    const float* h    = (const float*)d_in[0];
    const int*  eidx  = (const int*)d_in[1];
    const int*  etype = (const int*)d_in[2];
    const int*  numn  = (const int*)d_in[3];
    const float* Wm   = (const float*)d_in[4];
    const float* bm   = (const float*)d_in[5];
    const float* emb  = (const float*)d_in[6];
    const float* Wih  = (const float*)d_in[7];
    const float* Whh  = (const float*)d_in[8];
    const float* bih  = (const float*)d_in[9];
    const float* bhh  = (const float*)d_in[10];

    int N = in_sizes[0] / H;
    int E = in_sizes[2];

    // ws layout:
    unsigned short* h_b   = (unsigned short*)d_ws;               // N*H bf16
    unsigned short* Wcs   = h_b + (size_t)N * H;                 // 3*H*H (swizzled)
    unsigned short* Whhs  = Wcs + 3 * H * H;                     // 3*H*H (swizzled)
    unsigned short* embWs = Whhs + 3 * H * H;                    // 12288
    int* head4  = (int*)(embWs + 12288);                         // 4*N
    int* packed = head4 + 4 * N;                                 // E
    int* nexte  = packed + E;                                    // E

    int total8 = N * H / 8;
    int HB = (total8 + 255) / 256;
    int DB = (4 * N + 255) / 256;
    int PB = 264;
    fused_pre_kernel<<<HB + DB + PB, 256, 0, stream>>>(
        h, h_b, total8, head4, N, Wih, Whh, Wm, emb, bm,
        Wcs, Whhs, embWs, HB, DB);

    fill_ll_kernel<<<(E + 255) / 256, 256, 0, stream>>>(
        eidx, etype, head4, nexte, packed, E);

    gather_gru_kernel<<<(N + 63) / 64, 512, 0, stream>>>(
        h_b, head4, nexte, packed, Wcs, Whhs, embWs,
        bih, bhh, numn, (float*)d_out, N);
}